// Round 2
// baseline (152981.787 us; speedup 1.0000x reference)
//
#include <hip/hip_runtime.h>
#include <math.h>

// Echo-state network scan, persistent cooperative kernel, round 2.
// G=32 blocks x 512 threads. Each block owns 32 rows of W in registers
// (64 floats/thread). Per-step state exchange: self-validating 64-bit packets
// (tag<<32 | fp32), relaxed agent-scope atomics, tight spin poll (no sleeps).
// Output projection: rotating designated block computes the FULL out[t] row
// from its local copy of s_t (waves 4-7, hidden under the poll window),
// finalized next iteration. No atomics anywhere.

#define G_BLOCKS 32
#define ROWS     32     // rows per block
#define TPB      512
#define T_STEPS  32768
#define R_DIM    1024
#define IN_DIM   128
#define OUT_DIM  64

__global__ __launch_bounds__(TPB, 1)
void esn_scan_kernel(const float* __restrict__ x,     // [T][128]
                     const float* __restrict__ Win,   // [1024][128]
                     const float* __restrict__ W,     // [1024][1024]
                     const float* __restrict__ Wout,  // [1024][64]
                     float* __restrict__ out,         // [T][64]
                     unsigned long long* __restrict__ sbuf) // ws: [2][1024] u64
{
    constexpr float A       = 0.5f;   // leak rate
    constexpr float DEC     = 0.5f;   // 1 - leak rate
    constexpr float INV_DEC = 2.0f;

    const int b    = blockIdx.x;
    const int tid  = threadIdx.x;
    const int lane = tid & 63;
    const int wave = tid >> 6;        // 0..7
    const int r    = tid & 31;        // row within block chunk
    const int kg   = tid >> 5;        // k-group 0..15 (64 k each)

    __shared__ float s_dec[2][R_DIM];       // DEC*s_{t-1}, dbuf by parity
    __shared__ float part[16][ROWS];        // matvec partials [kg][row]
    __shared__ float part_out[16][OUT_DIM]; // out-projection partials
    __shared__ float u_lds[2][ROWS];        // input projection, dbuf
    __shared__ float x_lds[2][IN_DIM];      // prefetched inputs, dbuf
    __shared__ float win_lds[ROWS * 132];   // Win chunk, padded stride

    // ---- one-time setup ----
    float w[64];   // W[b*32+r][kg*64 .. +63]
    {
        const float* wrow = W + ((size_t)(b * ROWS + r)) * R_DIM + kg * 64;
        #pragma unroll
        for (int j = 0; j < 64; j += 4) {
            const float4 v = *(const float4*)(wrow + j);
            w[j] = v.x; w[j+1] = v.y; w[j+2] = v.z; w[j+3] = v.w;
        }
    }
    for (int i = tid; i < ROWS * IN_DIM; i += TPB) {
        int rr = i >> 7, cc = i & 127;
        win_lds[rr * 132 + cc] = Win[((size_t)(b * ROWS + rr)) * IN_DIM + cc];
    }
    for (int i = tid; i < R_DIM; i += TPB) s_dec[0][i] = 0.0f;  // s_{-1}=0
    if (tid < IN_DIM) {
        x_lds[0][tid] = x[tid];            // x_0
        x_lds[1][tid] = x[IN_DIM + tid];   // x_1
    }
    __syncthreads();

    // u_0 by wave 1
    if (wave == 1) {
        int rr = lane & 31, kh = lane >> 5;
        float acc = 0.f;
        const float* wl = &win_lds[rr * 132 + kh * 64];
        const float* xl = &x_lds[0][kh * 64];
        #pragma unroll
        for (int i = 0; i < 64; i += 4) {
            float4 wv = *(const float4*)(wl + i);
            float4 xv = *(const float4*)(xl + i);
            acc += wv.x*xv.x + wv.y*xv.y + wv.z*xv.z + wv.w*xv.w;
        }
        acc += __shfl_down(acc, 32);
        if (lane < 32) u_lds[0][rr] = acc;
    }
    __syncthreads();

    // ---- main scan: iters 0..T+1 (last two only drain the out pipeline) ----
    for (int t = 0; t <= T_STEPS + 1; ++t) {
        const bool scan = (t < T_STEPS);

        // Phase A: matvec partials. part[kg][r] = W[r][kg-span] . s_dec
        if (scan) {
            float a0 = 0.f, a1 = 0.f, a2 = 0.f, a3 = 0.f;
            const float* sp = &s_dec[t & 1][kg * 64];
            #pragma unroll
            for (int j = 0; j < 64; j += 4) {
                const float4 sv = *(const float4*)(sp + j);
                a0 += w[j]   * sv.x;
                a1 += w[j+1] * sv.y;
                a2 += w[j+2] * sv.z;
                a3 += w[j+3] * sv.w;
            }
            part[kg][r] = (a0 + a1) + (a2 + a3);
        }
        __syncthreads();

        // Phase B/C merged.
        if (scan) {
            if (wave == 0) {
                // critical path: reduce, tanh, publish own chunk
                if (lane < 32) {
                    float tot = 0.f;
                    #pragma unroll
                    for (int k = 0; k < 16; ++k) tot += part[k][lane];
                    const float y  = u_lds[t & 1][lane] + tot;
                    const float sd = s_dec[t & 1][b * ROWS + lane];
                    const float snew = sd + A * tanhf(y);
                    const unsigned long long pkt =
                        ((unsigned long long)(unsigned int)(t + 1) << 32)
                        | (unsigned long long)__float_as_uint(snew);
                    __hip_atomic_store(&sbuf[(size_t)(t & 1) * R_DIM + b * ROWS + lane],
                                       pkt, __ATOMIC_RELAXED, __HIP_MEMORY_SCOPE_AGENT);
                }
            } else if (wave == 1 && t + 1 < T_STEPS) {
                // off critical path: u_{t+1} + x prefetch
                const int tpre = (t + 2 < T_STEPS) ? (t + 2) : (T_STEPS - 1);
                const float xv0 = x[(size_t)tpre * IN_DIM + lane];
                const float xv1 = x[(size_t)tpre * IN_DIM + 64 + lane];
                int rr = lane & 31, kh = lane >> 5;
                float acc = 0.f;
                const float* wl = &win_lds[rr * 132 + kh * 64];
                const float* xl = &x_lds[(t + 1) & 1][kh * 64];
                #pragma unroll
                for (int i = 0; i < 64; i += 4) {
                    float4 wv = *(const float4*)(wl + i);
                    float4 xv = *(const float4*)(xl + i);
                    acc += wv.x*xv.x + wv.y*xv.y + wv.z*xv.z + wv.w*xv.w;
                }
                acc += __shfl_down(acc, 32);
                if (lane < 32) u_lds[(t + 1) & 1][rr] = acc;
                x_lds[t & 1][lane]      = xv0;
                x_lds[t & 1][64 + lane] = xv1;
            }
        }

        // Out-projection partials for step t-1 (designated block, waves 4-7):
        // out[t-1] = INV_DEC * s_dec[t&1] . Wout   (s_dec[t&1] = DEC*s_{t-1})
        if (wave >= 4 && t >= 1 && t <= T_STEPS && b == ((t - 1) & 31)) {
            const int j  = tid - 256;       // 0..255
            const int c4 = j & 15;          // col group: cols 4*c4..4*c4+3
            const int q  = j >> 4;          // row group: rows 64*q..64*q+63
            float4 acc = make_float4(0.f, 0.f, 0.f, 0.f);
            const float* wo = Wout + (size_t)(q * 64) * OUT_DIM + c4 * 4;
            const float* sv = &s_dec[t & 1][q * 64];
            #pragma unroll 8
            for (int rr = 0; rr < 64; ++rr) {
                const float s = sv[rr];
                const float4 wv = *(const float4*)(wo + (size_t)rr * OUT_DIM);
                acc.x += s * wv.x; acc.y += s * wv.y;
                acc.z += s * wv.z; acc.w += s * wv.w;
            }
            *(float4*)&part_out[q][c4 * 4] = acc;
        }

        // Finalize out[t-2] (previous designated block, wave 4)
        if (wave == 4 && t >= 2 && b == ((t - 2) & 31)) {
            float acc = 0.f;
            #pragma unroll
            for (int q = 0; q < 16; ++q) acc += part_out[q][lane];
            out[(size_t)(t - 2) * OUT_DIM + lane] = acc * INV_DEC;
        }

        // Poll: receive s_t (2 packets/thread), write s_dec[(t+1)&1]
        if (scan) {
            const int want = t + 1;
            const size_t base = (size_t)(t & 1) * R_DIM;
            unsigned long long v0 = __hip_atomic_load(&sbuf[base + tid],
                                        __ATOMIC_RELAXED, __HIP_MEMORY_SCOPE_AGENT);
            unsigned long long v1 = __hip_atomic_load(&sbuf[base + TPB + tid],
                                        __ATOMIC_RELAXED, __HIP_MEMORY_SCOPE_AGENT);
            while ((int)(v0 >> 32) != want)
                v0 = __hip_atomic_load(&sbuf[base + tid],
                                       __ATOMIC_RELAXED, __HIP_MEMORY_SCOPE_AGENT);
            while ((int)(v1 >> 32) != want)
                v1 = __hip_atomic_load(&sbuf[base + TPB + tid],
                                       __ATOMIC_RELAXED, __HIP_MEMORY_SCOPE_AGENT);
            s_dec[(t + 1) & 1][tid]       = __uint_as_float((unsigned int)v0) * DEC;
            s_dec[(t + 1) & 1][TPB + tid] = __uint_as_float((unsigned int)v1) * DEC;
        }
        __syncthreads();
    }
}

extern "C" void kernel_launch(void* const* d_in, const int* in_sizes, int n_in,
                              void* d_out, int out_size, void* d_ws, size_t ws_size,
                              hipStream_t stream) {
    const float* x    = (const float*)d_in[0];   // input_data  [32768][128]
    const float* Win  = (const float*)d_in[1];   // input_weights [1024][128]
    const float* W    = (const float*)d_in[2];   // reservoir_weights [1024][1024]
    const float* Wout = (const float*)d_in[3];   // output_weights [1024][64]
    float* out = (float*)d_out;                  // [32768][64]
    unsigned long long* sbuf = (unsigned long long*)d_ws;  // 16 KB used

    // every out element is written exactly once with a plain store -> no memset
    esn_scan_kernel<<<G_BLOCKS, TPB, 0, stream>>>(x, Win, W, Wout, out, sbuf);
}

// Round 3
// 135633.032 us; speedup vs baseline: 1.1279x; 1.1279x over previous
//
#include <hip/hip_runtime.h>
#include <math.h>

// ESN scan, round 3. 32 blocks x 256 threads, persistent.
// - W (x0.5 pre-folded) in registers: thread (c=tid&31, rset=tid>>5) holds
//   W[b*32+rset*4 .. +3][c*32 .. +31] = 128 VGPRs.
// - State exchange: 2 rows per u64 packet, each u32 = [tag8 | fp24]; thread
//   polls its own 32-value chunk (16 relaxed agent-scope u64 loads) straight
//   into registers. Lag<=1 step (induction) => 8-bit tag unambiguous.
// - Row sums via 5x shfl_xor inside the 32-lane half-wave; lanes c<2 finish
//   2 rows each (tanh, leak), stage packet+states in regs, store them at the
//   START of the next step (ack latency hides in the poll window).
// - ONE __syncthreads per step (protects x_lds/u_lds cross-wave handoff).
// - Output projection fully decoupled: states -> d_ws, second kernel GEMM.

#define G_BLOCKS 32
#define TPB      256
#define T_STEPS  32768
#define R_DIM    1024
#define IN_DIM   128
#define OUT_DIM  64

__device__ __forceinline__ float tanh_fast(float y) {
    float e = __expf(2.0f * y);            // v_exp_f32 path
    return 1.0f - 2.0f / (e + 1.0f);       // exact identity; |err| ~1e-7 abs
}

__device__ __forceinline__ unsigned pack24(float v, unsigned tag) {
    unsigned bts = __float_as_uint(v);
    bts = (bts + 0x80u) >> 8;              // round on dropped byte (|v|<2: no tag carry)
    return (tag << 24) | (bts & 0x00FFFFFFu);
}
__device__ __forceinline__ float unpack24(unsigned p) {
    return __uint_as_float(p << 8);
}

__global__ __launch_bounds__(TPB, 1)
void esn_scan(const float* __restrict__ x,     // [T][128]
              const float* __restrict__ Win,   // [1024][128]
              const float* __restrict__ W,     // [1024][1024]
              float* __restrict__ states,      // ws: [T][1024]
              unsigned long long* __restrict__ sbuf) // ws: [2][512] u64
{
    constexpr float A = 0.5f, DEC = 0.5f;
    const int b    = blockIdx.x;
    const int tid  = threadIdx.x;
    const int lane = tid & 63;
    const int wave = tid >> 6;             // 0..3
    const int c    = tid & 31;             // chunk id / lane-in-half-wave
    const int rset = tid >> 5;             // 0..7
    const bool is_pub = (c < 2);
    const int lrow0 = rset * 4 + 2 * c;    // publisher's first local row
    const int grow0 = b * 32 + lrow0;      // global row
    const int urow  = wave * 8 + (lane >> 3);  // u-mapping: intra-wave rows
    const int useg  = lane & 7;

    __shared__ float win_lds[32 * 132];    // Win chunk, padded stride
    __shared__ float x_lds[2][IN_DIM];     // x_{t+1} dbuf
    __shared__ float u_lds[2][32];         // u_t dbuf

    // ---- setup: W chunk -> regs, x0.5 folded (W @ (DEC*s) == (DEC*W) @ s) ----
    float w0[32], w1[32], w2[32], w3[32];
    {
        const float* base = W + (size_t)(b * 32 + rset * 4) * R_DIM + c * 32;
        #pragma unroll
        for (int k = 0; k < 32; k += 4) {
            float4 v0 = *(const float4*)(base + 0 * R_DIM + k);
            float4 v1 = *(const float4*)(base + 1 * R_DIM + k);
            float4 v2 = *(const float4*)(base + 2 * R_DIM + k);
            float4 v3 = *(const float4*)(base + 3 * R_DIM + k);
            w0[k]=v0.x*DEC; w0[k+1]=v0.y*DEC; w0[k+2]=v0.z*DEC; w0[k+3]=v0.w*DEC;
            w1[k]=v1.x*DEC; w1[k+1]=v1.y*DEC; w1[k+2]=v1.z*DEC; w1[k+3]=v1.w*DEC;
            w2[k]=v2.x*DEC; w2[k+1]=v2.y*DEC; w2[k+2]=v2.z*DEC; w2[k+3]=v2.w*DEC;
            w3[k]=v3.x*DEC; w3[k+1]=v3.y*DEC; w3[k+2]=v3.z*DEC; w3[k+3]=v3.w*DEC;
        }
    }
    for (int i = tid; i < 32 * IN_DIM; i += TPB) {
        int rr = i >> 7, cc = i & 127;
        win_lds[rr * 132 + cc] = Win[(size_t)(b * 32 + rr) * IN_DIM + cc];
    }
    float4 xr;   // deep x prefetch register (x_{t+2} at step-t phase 2)
    if (tid < 32) {
        *(float4*)&x_lds[0][tid * 4] = *(const float4*)(x + tid * 4);
        *(float4*)&x_lds[1][tid * 4] = *(const float4*)(x + IN_DIM + tid * 4);
        xr = *(const float4*)(x + 2 * IN_DIM + tid * 4);
    }
    __syncthreads();

    // u_0 (intra-wave: row urow by 8 lanes, 3-round oct reduce)
    {
        float up = 0.f;
        const float* wl = &win_lds[urow * 132 + useg * 16];
        const float* xl = &x_lds[0][useg * 16];
        #pragma unroll
        for (int j = 0; j < 16; j += 4) {
            float4 wv = *(const float4*)(wl + j);
            float4 xv = *(const float4*)(xl + j);
            up += wv.x*xv.x + wv.y*xv.y + wv.z*xv.z + wv.w*xv.w;
        }
        up += __shfl_xor(up, 1, 64);
        up += __shfl_xor(up, 2, 64);
        up += __shfl_xor(up, 4, 64);
        if (useg == 0) u_lds[0][urow] = up;
    }
    __syncthreads();

    float s_prev0 = 0.f, s_prev1 = 0.f;
    unsigned long long pub_pkt = 0;
    float pub_s0 = 0.f, pub_s1 = 0.f;

    for (int t = 0; t < T_STEPS; ++t) {
        // 0: publish step-(t-1) results NOW (store-ack hides in poll window)
        if (t > 0 && is_pub) {
            __hip_atomic_store(&sbuf[(size_t)(t & 1) * 512 + (grow0 >> 1)], pub_pkt,
                               __ATOMIC_RELAXED, __HIP_MEMORY_SCOPE_AGENT);
            *(float2*)&states[(size_t)(t - 1) * R_DIM + grow0] =
                make_float2(pub_s0, pub_s1);
        }
        // 1: issue poll loads early
        unsigned long long pk[16];
        const unsigned long long* sb = sbuf + (size_t)(t & 1) * 512 + c * 16;
        if (t > 0) {
            #pragma unroll
            for (int j = 0; j < 16; ++j)
                pk[j] = __hip_atomic_load(sb + j, __ATOMIC_RELAXED,
                                          __HIP_MEMORY_SCOPE_AGENT);
        }
        // 2: commit x_{t+2} to LDS, issue x_{t+3} prefetch
        if (tid < 32) {
            *(float4*)&x_lds[t & 1][tid * 4] = xr;
            const int tn = (t + 3 < T_STEPS) ? (t + 3) : (T_STEPS - 1);
            xr = *(const float4*)(x + (size_t)tn * IN_DIM + tid * 4);
        }
        // 3: u_{t+1} (independent of s_t — overlaps poll latency)
        {
            float up = 0.f;
            const float* wl = &win_lds[urow * 132 + useg * 16];
            const float* xl = &x_lds[(t + 1) & 1][useg * 16];
            #pragma unroll
            for (int j = 0; j < 16; j += 4) {
                float4 wv = *(const float4*)(wl + j);
                float4 xv = *(const float4*)(xl + j);
                up += wv.x*xv.x + wv.y*xv.y + wv.z*xv.z + wv.w*xv.w;
            }
            up += __shfl_xor(up, 1, 64);
            up += __shfl_xor(up, 2, 64);
            up += __shfl_xor(up, 4, 64);
            if (useg == 0) u_lds[(t + 1) & 1][urow] = up;
        }
        // 4: spin until all 32 tag bytes match, unpack to regs
        float sd[32];
        if (t > 0) {
            const unsigned tg = (unsigned)(t & 255);
            int spins = 0;
            while (true) {
                bool ok = true;
                #pragma unroll
                for (int j = 0; j < 16; ++j) {
                    unsigned lo = (unsigned)pk[j], hi = (unsigned)(pk[j] >> 32);
                    ok &= ((lo >> 24) == tg) & ((hi >> 24) == tg);
                }
                if (ok) break;
                if (++spins > 8) __builtin_amdgcn_s_sleep(1);
                #pragma unroll
                for (int j = 0; j < 16; ++j)
                    pk[j] = __hip_atomic_load(sb + j, __ATOMIC_RELAXED,
                                              __HIP_MEMORY_SCOPE_AGENT);
            }
            #pragma unroll
            for (int j = 0; j < 16; ++j) {
                sd[2 * j]     = unpack24((unsigned)pk[j]);
                sd[2 * j + 1] = unpack24((unsigned)(pk[j] >> 32));
            }
        } else {
            #pragma unroll
            for (int k = 0; k < 32; ++k) sd[k] = 0.f;
        }
        // 5: 128 FMAs (4 rows x 32 k), W pre-scaled by DEC
        float a0 = 0.f, a1 = 0.f, a2 = 0.f, a3 = 0.f;
        #pragma unroll
        for (int k = 0; k < 32; ++k) {
            a0 += w0[k] * sd[k]; a1 += w1[k] * sd[k];
            a2 += w2[k] * sd[k]; a3 += w3[k] * sd[k];
        }
        // 6: half-wave butterfly (masks <=16 stay within the 32-lane half)
        #pragma unroll
        for (int m = 1; m <= 16; m <<= 1) {
            a0 += __shfl_xor(a0, m, 64);
            a1 += __shfl_xor(a1, m, 64);
            a2 += __shfl_xor(a2, m, 64);
            a3 += __shfl_xor(a3, m, 64);
        }
        // 7: publishers (c<2) finish 2 rows, stage packet + states
        if (is_pub) {
            const float r0 = (c == 0) ? a0 : a2;
            const float r1 = (c == 0) ? a1 : a3;
            const float y0 = u_lds[t & 1][lrow0]     + r0;
            const float y1 = u_lds[t & 1][lrow0 + 1] + r1;
            const float s0 = DEC * s_prev0 + A * tanh_fast(y0);
            const float s1 = DEC * s_prev1 + A * tanh_fast(y1);
            s_prev0 = s0; s_prev1 = s1;
            const unsigned tg1 = (unsigned)((t + 1) & 255);
            pub_pkt = ((unsigned long long)pack24(s1, tg1) << 32) | pack24(s0, tg1);
            pub_s0 = s0; pub_s1 = s1;
        }
        __syncthreads();   // protects u_lds / x_lds cross-wave handoff
    }
    // flush final staged states row (step T-1)
    if (is_pub)
        *(float2*)&states[(size_t)(T_STEPS - 1) * R_DIM + grow0] =
            make_float2(pub_s0, pub_s1);
}

// ---- kernel 2: out = states @ Wout  ([32768x1024] x [1024x64]) ----
__global__ __launch_bounds__(256)
void out_gemm(const float* __restrict__ states,
              const float* __restrict__ Wout,
              float* __restrict__ out)
{
    __shared__ float st[64][132];     // 64 t-rows x 128 k (padded)
    __shared__ float wt[128][64];     // 128 k x 64 cols
    const int t0  = blockIdx.x * 64;
    const int tid = threadIdx.x;
    const int tl  = tid >> 2;         // 0..63 t-local
    const int cg  = tid & 3;          // 16-col group
    float acc[16];
    #pragma unroll
    for (int j = 0; j < 16; ++j) acc[j] = 0.f;

    for (int kt = 0; kt < R_DIM; kt += 128) {
        const float* src = states + (size_t)(t0 + tl) * R_DIM + kt + cg * 32;
        #pragma unroll
        for (int q = 0; q < 8; ++q)
            *(float4*)&st[tl][cg * 32 + q * 4] = *(const float4*)(src + q * 4);
        const float* wsrc = Wout + (size_t)(kt + (tid >> 1)) * OUT_DIM + (tid & 1) * 32;
        #pragma unroll
        for (int q = 0; q < 8; ++q)
            *(float4*)&wt[tid >> 1][(tid & 1) * 32 + q * 4] = *(const float4*)(wsrc + q * 4);
        __syncthreads();
        #pragma unroll 4
        for (int k = 0; k < 128; ++k) {
            const float s = st[tl][k];
            const float* wr = &wt[k][cg * 16];
            #pragma unroll
            for (int j = 0; j < 16; ++j) acc[j] += s * wr[j];
        }
        __syncthreads();
    }
    float* op = out + (size_t)(t0 + tl) * OUT_DIM + cg * 16;
    #pragma unroll
    for (int q = 0; q < 4; ++q) *(float4*)(op + q * 4) = *(float4*)&acc[q * 4];
}

extern "C" void kernel_launch(void* const* d_in, const int* in_sizes, int n_in,
                              void* d_out, int out_size, void* d_ws, size_t ws_size,
                              hipStream_t stream) {
    const float* x    = (const float*)d_in[0];   // input_data  [32768][128]
    const float* Win  = (const float*)d_in[1];   // input_weights [1024][128]
    const float* W    = (const float*)d_in[2];   // reservoir_weights [1024][1024]
    const float* Wout = (const float*)d_in[3];   // output_weights [1024][64]
    float* out = (float*)d_out;                  // [32768][64]

    unsigned long long* sbuf = (unsigned long long*)d_ws;          // 8 KB used
    float* states = (float*)((char*)d_ws + 65536);                 // 128 MiB

    esn_scan<<<G_BLOCKS, TPB, 0, stream>>>(x, Win, W, states, sbuf);
    out_gemm<<<T_STEPS / 64, 256, 0, stream>>>(states, Wout, out);
}

// Round 5
// 98854.456 us; speedup vs baseline: 1.5475x; 1.3720x over previous
//
#include <hip/hip_runtime.h>
#include <math.h>

// ESN scan, round 5 = round 4 with the swizzle double-application fixed.
// 32 blocks x 256 threads, persistent. W (xDEC pre-folded, NATURAL order) in
// 32 float4 regs/thread. Wave 3 is the only poller: 64 lanes x 8 u64 packets
// (tag8|fp24 x2), stale-only reloads, sleep-throttled; it stores into a
// ROTATED LDS state buffer (element e of chunk c at position (e+4c)&31).
// Consumers read at position (4q+4c)&31 -> element 4q in natural order ->
// multiply by natural-order W regs. The single per-step __syncthreads both
// publishes the LDS buffer AND proves packet validity block-wide. Publish of
// s_{t+1} is immediate after tanh so the inter-block critical path is
// store -> L3 -> poll with no barrier on it.

#define G_BLOCKS 32
#define TPB      256
#define T_STEPS  32768
#define R_DIM    1024
#define IN_DIM   128
#define OUT_DIM  64

__device__ __forceinline__ float tanh_fast(float y) {
    float e = __expf(2.0f * y);
    return 1.0f - 2.0f / (e + 1.0f);
}
__device__ __forceinline__ unsigned pack24(float v, unsigned tag) {
    unsigned bts = __float_as_uint(v);
    bts = (bts + 0x80u) >> 8;              // |v|<=1 -> no carry into tag byte
    return (tag << 24) | (bts & 0x00FFFFFFu);
}
__device__ __forceinline__ float unpack24(unsigned p) {
    return __uint_as_float(p << 8);
}

__global__ __launch_bounds__(TPB, 1)
void esn_scan(const float* __restrict__ x,     // [T][128]
              const float* __restrict__ Win,   // [1024][128]
              const float* __restrict__ W,     // [1024][1024]
              float* __restrict__ states,      // ws: [T][1024]
              unsigned long long* __restrict__ sbuf) // ws: [2][512] u64
{
    constexpr float A = 0.5f, DEC = 0.5f;
    const int b    = blockIdx.x;
    const int tid  = threadIdx.x;
    const int c    = tid & 31;             // k-chunk (32 floats each)
    const int rset = tid >> 5;             // 0..7 -> 4 rows
    const bool is_pub = (c < 2);
    const int lrow0 = rset * 4 + 2 * c;    // publisher's first local row
    const int grow0 = b * 32 + lrow0;      // global row (even)

    __shared__ float s_lds[2][R_DIM];      // raw s_t, ROTATED storage, dbuf
    __shared__ float u_lds[2][32];         // u_t, dbuf parity
    __shared__ float x_lds[2][IN_DIM];     // x_t, dbuf parity
    __shared__ float win_lds[32 * 132];    // Win chunk, padded stride

    // ---- setup ----
    // W regs, DEC-folded, NATURAL order: w?v[q] = W[row][c*32 + 4q .. +3]
    float4 w0v[8], w1v[8], w2v[8], w3v[8];
    {
        const float* base = W + (size_t)(b * 32 + rset * 4) * R_DIM + c * 32;
        #pragma unroll
        for (int q = 0; q < 8; ++q) {
            const float4 v0 = *(const float4*)(base + 0 * R_DIM + 4 * q);
            const float4 v1 = *(const float4*)(base + 1 * R_DIM + 4 * q);
            const float4 v2 = *(const float4*)(base + 2 * R_DIM + 4 * q);
            const float4 v3 = *(const float4*)(base + 3 * R_DIM + 4 * q);
            w0v[q] = make_float4(v0.x*DEC, v0.y*DEC, v0.z*DEC, v0.w*DEC);
            w1v[q] = make_float4(v1.x*DEC, v1.y*DEC, v1.z*DEC, v1.w*DEC);
            w2v[q] = make_float4(v2.x*DEC, v2.y*DEC, v2.z*DEC, v2.w*DEC);
            w3v[q] = make_float4(v3.x*DEC, v3.y*DEC, v3.z*DEC, v3.w*DEC);
        }
    }
    for (int i = tid; i < 32 * IN_DIM; i += TPB) {
        int rr = i >> 7, cc = i & 127;
        win_lds[rr * 132 + cc] = Win[(size_t)(b * 32 + rr) * IN_DIM + cc];
    }
    for (int i = tid; i < R_DIM; i += TPB) { s_lds[0][i] = 0.f; s_lds[1][i] = 0.f; }
    if (tid < 32) {
        *(float4*)&x_lds[0][tid * 4] = *(const float4*)(x + tid * 4);           // x_0
        *(float4*)&x_lds[1][tid * 4] = *(const float4*)(x + IN_DIM + tid * 4);  // x_1
    }
    float4 xr = make_float4(0.f, 0.f, 0.f, 0.f);   // wave2 lanes 0..31: x_{t+2}
    if (tid >= 128 && tid < 160)
        xr = *(const float4*)(x + 2 * IN_DIM + (tid - 128) * 4);
    __syncthreads();

    // u_0 (waves 0-1: row=tid>>2, seg=tid&3, 32 K each, 2-round shfl)
    if (tid < 128) {
        const int row = tid >> 2, seg = tid & 3;
        const float* wl = &win_lds[row * 132 + seg * 32];
        const float* xl = &x_lds[0][seg * 32];
        float acc = 0.f;
        #pragma unroll
        for (int j = 0; j < 32; j += 4) {
            float4 wv = *(const float4*)(wl + j);
            float4 xv = *(const float4*)(xl + j);
            acc += wv.x*xv.x + wv.y*xv.y + wv.z*xv.z + wv.w*xv.w;
        }
        acc += __shfl_xor(acc, 1);
        acc += __shfl_xor(acc, 2);
        if (seg == 0) u_lds[0][row] = acc;
    }
    __syncthreads();

    float s_prev0 = 0.f, s_prev1 = 0.f;

    for (int t = 0; t < T_STEPS; ++t) {
        // ---- D phase (pre-barrier, roles disjoint) ----
        if (tid < 128) {
            // u_{t+1} -> u_lds[(t+1)&1]
            const int row = tid >> 2, seg = tid & 3;
            const float* wl = &win_lds[row * 132 + seg * 32];
            const float* xl = &x_lds[(t + 1) & 1][seg * 32];
            float acc = 0.f;
            #pragma unroll
            for (int j = 0; j < 32; j += 4) {
                float4 wv = *(const float4*)(wl + j);
                float4 xv = *(const float4*)(xl + j);
                acc += wv.x*xv.x + wv.y*xv.y + wv.z*xv.z + wv.w*xv.w;
            }
            acc += __shfl_xor(acc, 1);
            acc += __shfl_xor(acc, 2);
            if (seg == 0) u_lds[(t + 1) & 1][row] = acc;
        } else if (tid < 160) {
            // commit x_{t+2} into buf t&1, prefetch x_{t+3}
            const int xt = tid - 128;
            *(float4*)&x_lds[t & 1][xt * 4] = xr;
            const int tn = (t + 3 < T_STEPS) ? (t + 3) : (T_STEPS - 1);
            xr = *(const float4*)(x + (size_t)tn * IN_DIM + xt * 4);
        } else if (tid >= 192 && t > 0) {
            // delegated poll: lane l owns 8 packets = rows 16l..16l+15
            const int l = tid - 192;
            const unsigned long long* sb = sbuf + (size_t)(t & 1) * 512 + l * 8;
            unsigned long long pk[8];
            unsigned valid = 0;
            const unsigned tg = (unsigned)(t & 255);
            int pass = 0;
            while (valid != 0xFFu) {
                #pragma unroll
                for (int j = 0; j < 8; ++j)
                    if (!(valid & (1u << j)))
                        pk[j] = __hip_atomic_load(sb + j, __ATOMIC_RELAXED,
                                                  __HIP_MEMORY_SCOPE_AGENT);
                #pragma unroll
                for (int j = 0; j < 8; ++j) {
                    if (!(valid & (1u << j))) {
                        unsigned lo = (unsigned)pk[j], hi = (unsigned)(pk[j] >> 32);
                        if (((lo >> 24) == tg) && ((hi >> 24) == tg))
                            valid |= (1u << j);
                    }
                }
                if (valid != 0xFFu && ++pass > 1) __builtin_amdgcn_s_sleep(1);
            }
            float val[16];
            #pragma unroll
            for (int j = 0; j < 8; ++j) {
                val[2 * j]     = unpack24((unsigned)pk[j]);
                val[2 * j + 1] = unpack24((unsigned)(pk[j] >> 32));
            }
            // ROTATED store: element e=eb+4q of chunk cc at pos (e+4cc)&31
            const int cc = l >> 1, eb = 16 * (l & 1);
            float* dst = &s_lds[t & 1][cc * 32];
            #pragma unroll
            for (int q = 0; q < 4; ++q) {
                const int idx = ((eb + 4 * q) + 4 * cc) & 31;
                *(float4*)(dst + idx) = *(float4*)&val[4 * q];
            }
        }
        // pub's u preload (pre-barrier: avoids WAR race with next-iter writer)
        float up0 = 0.f, up1 = 0.f;
        if (is_pub) { up0 = u_lds[t & 1][lrow0]; up1 = u_lds[t & 1][lrow0 + 1]; }
        __syncthreads();

        // ---- F phase: matvec from rotated LDS.
        // Read pos (4q+4c)&31 -> element 4q (natural); W regs natural order.
        float a0 = 0.f, a1 = 0.f, a2 = 0.f, a3 = 0.f;
        {
            const float* sp = &s_lds[t & 1][c * 32];
            #pragma unroll
            for (int q = 0; q < 8; ++q) {
                const int off = (4 * q + 4 * c) & 31;
                const float4 sv = *(const float4*)(sp + off);
                a0 += w0v[q].x*sv.x + w0v[q].y*sv.y + w0v[q].z*sv.z + w0v[q].w*sv.w;
                a1 += w1v[q].x*sv.x + w1v[q].y*sv.y + w1v[q].z*sv.z + w1v[q].w*sv.w;
                a2 += w2v[q].x*sv.x + w2v[q].y*sv.y + w2v[q].z*sv.z + w2v[q].w*sv.w;
                a3 += w3v[q].x*sv.x + w3v[q].y*sv.y + w3v[q].z*sv.z + w3v[q].w*sv.w;
            }
        }
        // wait: sv loaded at rotated pos is element 4q of the chunk, and w?v[q]
        // is W[row][c*32+4q] -> pairing correct.
        #pragma unroll
        for (int m = 1; m <= 16; m <<= 1) {
            a0 += __shfl_xor(a0, m);
            a1 += __shfl_xor(a1, m);
            a2 += __shfl_xor(a2, m);
            a3 += __shfl_xor(a3, m);
        }
        if (is_pub) {
            const float r0 = (c == 0) ? a0 : a2;
            const float r1 = (c == 0) ? a1 : a3;
            const float s0 = DEC * s_prev0 + A * tanh_fast(up0 + r0);
            const float s1 = DEC * s_prev1 + A * tanh_fast(up1 + r1);
            s_prev0 = s0; s_prev1 = s1;
            const unsigned tg1 = (unsigned)((t + 1) & 255);
            const unsigned long long pkt =
                ((unsigned long long)pack24(s1, tg1) << 32) | pack24(s0, tg1);
            __hip_atomic_store(&sbuf[(size_t)((t + 1) & 1) * 512 + (grow0 >> 1)],
                               pkt, __ATOMIC_RELAXED, __HIP_MEMORY_SCOPE_AGENT);
            *(float2*)&states[(size_t)t * R_DIM + grow0] = make_float2(s0, s1);
        }
    }
}

// ---- kernel 2: out = states @ Wout ----
__global__ __launch_bounds__(256)
void out_gemm(const float* __restrict__ states,
              const float* __restrict__ Wout,
              float* __restrict__ out)
{
    __shared__ float st[64][132];
    __shared__ float wt[128][64];
    const int t0  = blockIdx.x * 64;
    const int tid = threadIdx.x;
    const int tl  = tid >> 2;
    const int cg  = tid & 3;
    float acc[16];
    #pragma unroll
    for (int j = 0; j < 16; ++j) acc[j] = 0.f;

    for (int kt = 0; kt < R_DIM; kt += 128) {
        const float* src = states + (size_t)(t0 + tl) * R_DIM + kt + cg * 32;
        #pragma unroll
        for (int q = 0; q < 8; ++q)
            *(float4*)&st[tl][cg * 32 + q * 4] = *(const float4*)(src + q * 4);
        const float* wsrc = Wout + (size_t)(kt + (tid >> 1)) * OUT_DIM + (tid & 1) * 32;
        #pragma unroll
        for (int q = 0; q < 8; ++q)
            *(float4*)&wt[tid >> 1][(tid & 1) * 32 + q * 4] = *(const float4*)(wsrc + q * 4);
        __syncthreads();
        #pragma unroll 4
        for (int k = 0; k < 128; ++k) {
            const float s = st[tl][k];
            const float* wr = &wt[k][cg * 16];
            #pragma unroll
            for (int j = 0; j < 16; ++j) acc[j] += s * wr[j];
        }
        __syncthreads();
    }
    float* op = out + (size_t)(t0 + tl) * OUT_DIM + cg * 16;
    #pragma unroll
    for (int q = 0; q < 4; ++q) *(float4*)(op + q * 4) = *(float4*)&acc[q * 4];
}

extern "C" void kernel_launch(void* const* d_in, const int* in_sizes, int n_in,
                              void* d_out, int out_size, void* d_ws, size_t ws_size,
                              hipStream_t stream) {
    const float* x    = (const float*)d_in[0];
    const float* Win  = (const float*)d_in[1];
    const float* W    = (const float*)d_in[2];
    const float* Wout = (const float*)d_in[3];
    float* out = (float*)d_out;

    unsigned long long* sbuf = (unsigned long long*)d_ws;   // 8 KB used
    float* states = (float*)((char*)d_ws + 65536);          // 128 MiB

    esn_scan<<<G_BLOCKS, TPB, 0, stream>>>(x, Win, W, states, sbuf);
    out_gemm<<<T_STEPS / 64, 256, 0, stream>>>(states, Wout, out);
}